// Round 5
// baseline (226.702 us; speedup 1.0000x reference)
//
#include <hip/hip_runtime.h>
#include <hip/hip_bf16.h>

// B=2, N=2048, C=1024, H=16, D=64, SCALE=0.125
// out0 = (attn(x)+f) @ W_proj + b_proj ; out1 = attn2gcn
#define OUT1_OFF 4194304
#define QSCALE 0.1803368801111204f   // 0.125 * log2(e)

typedef __attribute__((ext_vector_type(8))) short bf16x8;
typedef __attribute__((ext_vector_type(4))) float f32x4;

__device__ __forceinline__ unsigned short f2bf(float x) {
    unsigned u = __float_as_uint(x);
    u += 0x7FFFu + ((u >> 16) & 1u);
    return (unsigned short)(u >> 16);
}

// async global->LDS, 16B per lane. dst must be base + lane*16 (contiguous).
__device__ __forceinline__ void gl2lds16(const unsigned short* g, unsigned short* l) {
    __builtin_amdgcn_global_load_lds(
        (const __attribute__((address_space(1))) unsigned int*)g,
        (__attribute__((address_space(3))) unsigned int*)l, 16, 0, 0);
}

__global__ __launch_bounds__(256) void cvt_bf16(const float* __restrict__ s,
                                                unsigned short* __restrict__ d, int n4) {
    int i = blockIdx.x * 256 + threadIdx.x;
    if (i >= n4) return;
    float4 v = reinterpret_cast<const float4*>(s)[i];
    ushort4 o = make_ushort4(f2bf(v.x), f2bf(v.y), f2bf(v.z), f2bf(v.w));
    reinterpret_cast<ushort4*>(d)[i] = o;
}

// Transpose+convert: in (Kd,Nd) f32 -> out (Nd,Kd) bf16.
__global__ __launch_bounds__(256) void cvt_t(const float* __restrict__ in,
                                             unsigned short* __restrict__ out,
                                             int Kd, int Nd) {
    __shared__ float T[64][65];
    const int tid = threadIdx.x;
    const int r0 = blockIdx.y * 64, c0 = blockIdx.x * 64;
    const int tr = tid >> 3, tc = (tid & 7) * 8;
#pragma unroll
    for (int rr = 0; rr < 64; rr += 32) {
        const float4* p = reinterpret_cast<const float4*>(&in[(r0 + tr + rr) * Nd + c0 + tc]);
        float4 v0 = p[0], v1 = p[1];
        T[tr + rr][tc + 0] = v0.x; T[tr + rr][tc + 1] = v0.y;
        T[tr + rr][tc + 2] = v0.z; T[tr + rr][tc + 3] = v0.w;
        T[tr + rr][tc + 4] = v1.x; T[tr + rr][tc + 5] = v1.y;
        T[tr + rr][tc + 6] = v1.z; T[tr + rr][tc + 7] = v1.w;
    }
    __syncthreads();
#pragma unroll
    for (int rr = 0; rr < 64; rr += 32) {
        int orow = tr + rr;
        ushort4 o0 = make_ushort4(f2bf(T[tc + 0][orow]), f2bf(T[tc + 1][orow]),
                                  f2bf(T[tc + 2][orow]), f2bf(T[tc + 3][orow]));
        ushort4 o1 = make_ushort4(f2bf(T[tc + 4][orow]), f2bf(T[tc + 5][orow]),
                                  f2bf(T[tc + 6][orow]), f2bf(T[tc + 7][orow]));
        unsigned short* dst = &out[(c0 + orow) * Kd + r0 + tc];
        *reinterpret_cast<ushort4*>(dst) = o0;
        *reinterpret_cast<ushort4*>(dst + 4) = o1;
    }
}

// ---------------------------------------------------------------------------
// GEMM1 (m97-style): x(4096,1024) @ WqkvT(3072,1024)^T. 128x128 tile, BK=64,
// 4 waves 2x2 (wave 64x64). global_load_lds staging, XOR-swizzled LDS.
// Epilogue scatters q(*QSCALE), k, and V into contiguous per-64-key 8KB tiles
// with in-group key permutation tokp (matches attn P order).
// ---------------------------------------------------------------------------
__global__ __launch_bounds__(256) void gemm_qkv(const unsigned short* __restrict__ A,
                                                const unsigned short* __restrict__ Bt,
                                                unsigned short* __restrict__ qb,
                                                unsigned short* __restrict__ kb,
                                                unsigned short* __restrict__ vtb) {
    __shared__ __align__(16) unsigned short As[8192];
    __shared__ __align__(16) unsigned short Bs[8192];
    const int tid = threadIdx.x;
    const int w = tid >> 6, lane = tid & 63, quad = lane >> 4, l15 = lane & 15;
    const int m0 = blockIdx.y * 128, n0 = blockIdx.x * 128;
    const int wm = (w & 1) * 64, wn = (w >> 1) * 64;
    const int sw = (l15 & 7) << 3;
    f32x4 acc[4][4] = {};
    for (int k0 = 0; k0 < 1024; k0 += 64) {
        __syncthreads();
#pragma unroll
        for (int t = 0; t < 4; ++t) {
            int c = t * 256 + tid;
            int row = c >> 3, jg = ((c & 7) ^ (row & 7)) * 8;
            gl2lds16(&A[(m0 + row) * 1024 + k0 + jg], &As[c * 8]);
            gl2lds16(&Bt[(n0 + row) * 1024 + k0 + jg], &Bs[c * 8]);
        }
        __syncthreads();
#pragma unroll
        for (int kk = 0; kk < 2; ++kk) {
            bf16x8 af[4], bfr[4];
#pragma unroll
            for (int i = 0; i < 4; ++i)
                af[i] = *reinterpret_cast<const bf16x8*>(
                    &As[(wm + i * 16 + l15) * 64 + ((((kk * 4 + quad) << 3) ^ sw))]);
#pragma unroll
            for (int j = 0; j < 4; ++j)
                bfr[j] = *reinterpret_cast<const bf16x8*>(
                    &Bs[(wn + j * 16 + l15) * 64 + ((((kk * 4 + quad) << 3) ^ sw))]);
#pragma unroll
            for (int i = 0; i < 4; ++i)
#pragma unroll
                for (int j = 0; j < 4; ++j)
                    acc[i][j] = __builtin_amdgcn_mfma_f32_16x16x32_bf16(af[i], bfr[j], acc[i][j], 0, 0, 0);
        }
    }
#pragma unroll
    for (int j = 0; j < 4; ++j) {
        int n = n0 + wn + j * 16 + l15;
        int t = n >> 10, h = (n & 1023) >> 6, dd = n & 63;
#pragma unroll
        for (int i = 0; i < 4; ++i)
#pragma unroll
            for (int r = 0; r < 4; ++r) {
                int m = m0 + wm + i * 16 + quad * 4 + r;
                int b = m >> 11, tok = m & 2047;
                float v = acc[i][j][r];
                if (t == 0)      qb[(((b * 16 + h) * 2048) + tok) * 64 + dd] = f2bf(v * QSCALE);
                else if (t == 1) kb[(((b * 16 + h) * 2048) + tok) * 64 + dd] = f2bf(v);
                else {
                    int tokp = ((tok & 15) << 2) | ((tok >> 4) & 3);
                    vtb[((((b * 16 + h) * 32 + (tok >> 6)) * 64) + dd) * 64 + tokp] = f2bf(v);
                }
            }
    }
}

// ---------------------------------------------------------------------------
// Attention: 1024 blocks (32 qtiles x 32 bh, XCD-swizzled), 4 waves x 16 q rows.
// K/V 64-key tiles staged via global_load_lds, double-buffered, one
// __syncthreads per tile. Fixed-max softmax with raw v_exp_f32 + v_perm pack.
// P transpose: per-wave LDS + double lgkm fence (proven R3/R4).
// LDS: 2*8K K + 2*8K V + 9K P = 41KB -> 3 blocks/CU (24 waves/CU).
// ---------------------------------------------------------------------------
__global__ __launch_bounds__(256) void attn_kernel(const unsigned short* __restrict__ qb,
                                                   const unsigned short* __restrict__ kb,
                                                   const unsigned short* __restrict__ vtb,
                                                   const float* __restrict__ f,
                                                   float* __restrict__ attn2_out,
                                                   unsigned short* __restrict__ fusedb) {
    __shared__ __align__(16) unsigned short Ksw[2][4096];
    __shared__ __align__(16) unsigned short Vsw[2][4096];
    __shared__ __align__(16) unsigned short Ps[4][16][72];
    const int tid = threadIdx.x;
    const int w = tid >> 6, lane = tid & 63, quad = lane >> 4, l15 = lane & 15;
    const int bid = blockIdx.x;
    const int qtile = bid >> 5;
    const int bh = (bid & 7) * 4 + ((bid >> 3) & 3);   // same bh -> same XCD
    const int q0 = qtile * 64 + w * 16;
    const unsigned short* qr = &qb[(bh * 2048 + q0 + l15) * 64 + quad * 8];
    bf16x8 a0 = *reinterpret_cast<const bf16x8*>(qr);
    bf16x8 a1 = *reinterpret_cast<const bf16x8*>(qr + 32);
    const unsigned short* kt0 = kb + bh * 131072;
    const unsigned short* vt0 = vtb + bh * 131072;
    // staging: 256 threads x 2 chunks each per 8KB tile
    const int c1 = tid, c2 = tid + 256;
    const int gu1 = (((c1 & ~7) | ((c1 & 7) ^ ((c1 >> 3) & 7))) << 3);
    const int gu2 = (((c2 & ~7) | ((c2 & 7) ^ ((c2 >> 3) & 7))) << 3);
    const int sw = (l15 & 7) << 3;
    f32x4 O[4] = {};
    float lsum[4] = {0.f, 0.f, 0.f, 0.f};

    gl2lds16(kt0 + gu1, &Ksw[0][c1 * 8]);
    gl2lds16(kt0 + gu2, &Ksw[0][c2 * 8]);
    gl2lds16(vt0 + gu1, &Vsw[0][c1 * 8]);
    gl2lds16(vt0 + gu2, &Vsw[0][c2 * 8]);

    int buf = 0;
    for (int it = 0; it < 32; ++it, buf ^= 1) {
        __syncthreads();    // drains vmcnt: tile[buf] resident; WAR for buf^1
        if (it < 31) {
            int toff = (it + 1) * 4096;
            gl2lds16(kt0 + toff + gu1, &Ksw[buf ^ 1][c1 * 8]);
            gl2lds16(kt0 + toff + gu2, &Ksw[buf ^ 1][c2 * 8]);
            gl2lds16(vt0 + toff + gu1, &Vsw[buf ^ 1][c1 * 8]);
            gl2lds16(vt0 + toff + gu2, &Vsw[buf ^ 1][c2 * 8]);
        }
        f32x4 S[4];
#pragma unroll
        for (int s = 0; s < 4; ++s) {
            int krow = (s * 16 + l15) * 64;
            bf16x8 b0 = *reinterpret_cast<const bf16x8*>(&Ksw[buf][krow + ((quad << 3) ^ sw)]);
            bf16x8 b1 = *reinterpret_cast<const bf16x8*>(&Ksw[buf][krow + (((quad + 4) << 3) ^ sw)]);
            f32x4 z = {};
            z = __builtin_amdgcn_mfma_f32_16x16x32_bf16(a0, b0, z, 0, 0, 0);
            z = __builtin_amdgcn_mfma_f32_16x16x32_bf16(a1, b1, z, 0, 0, 0);
            S[s] = z;
        }
#pragma unroll
        for (int r = 0; r < 4; ++r) {
            float p0 = __builtin_amdgcn_exp2f(S[0][r]);
            float p1 = __builtin_amdgcn_exp2f(S[1][r]);
            float p2 = __builtin_amdgcn_exp2f(S[2][r]);
            float p3 = __builtin_amdgcn_exp2f(S[3][r]);
            lsum[r] += (p0 + p1) + (p2 + p3);
            unsigned D01 = __builtin_amdgcn_perm(__float_as_uint(p1), __float_as_uint(p0), 0x07060302u);
            unsigned D23 = __builtin_amdgcn_perm(__float_as_uint(p3), __float_as_uint(p2), 0x07060302u);
            *reinterpret_cast<uint2*>(&Ps[w][quad * 4 + r][l15 * 4]) = make_uint2(D01, D23);
        }
        asm volatile("s_waitcnt lgkmcnt(0)" ::: "memory");   // RAW: P stores retired
        bf16x8 pa0 = *reinterpret_cast<const bf16x8*>(&Ps[w][l15][quad * 8]);
        bf16x8 pa1 = *reinterpret_cast<const bf16x8*>(&Ps[w][l15][32 + quad * 8]);
        asm volatile("s_waitcnt lgkmcnt(0)" ::: "memory");   // WAR: P reads in VGPRs
#pragma unroll
        for (int c4 = 0; c4 < 4; ++c4) {
            int vrow = (c4 * 16 + l15) * 64;
            bf16x8 v0 = *reinterpret_cast<const bf16x8*>(&Vsw[buf][vrow + ((quad << 3) ^ sw)]);
            bf16x8 v1 = *reinterpret_cast<const bf16x8*>(&Vsw[buf][vrow + (((quad + 4) << 3) ^ sw)]);
            O[c4] = __builtin_amdgcn_mfma_f32_16x16x32_bf16(pa0, v0, O[c4], 0, 0, 0);
            O[c4] = __builtin_amdgcn_mfma_f32_16x16x32_bf16(pa1, v1, O[c4], 0, 0, 0);
        }
    }
#pragma unroll
    for (int r = 0; r < 4; ++r) {
        float s = lsum[r];
#pragma unroll
        for (int off = 8; off > 0; off >>= 1) s += __shfl_xor(s, off, 16);
        lsum[r] = 1.f / s;
    }
    const int b = bh >> 4, h = bh & 15;
#pragma unroll
    for (int r = 0; r < 4; ++r) {
        int tok = q0 + quad * 4 + r;
        int base = (b * 2048 + tok) * 1024 + h * 64;
#pragma unroll
        for (int c4 = 0; c4 < 4; ++c4) {
            int col = c4 * 16 + l15;
            float o = O[c4][r] * lsum[r];
            attn2_out[base + col] = o;
            fusedb[base + col] = f2bf(o + f[base + col]);
        }
    }
}

// ---------------------------------------------------------------------------
// GEMM2 (m97-style): fused(4096,1024) @ WprojT(1024,1024)^T + bias -> out f32.
// 128x64 tile (4 waves 2x2, wave 64x32), grid (16,32)=512 -> 2 blocks/CU.
// ---------------------------------------------------------------------------
__global__ __launch_bounds__(256) void gemm_proj(const unsigned short* __restrict__ A,
                                                 const unsigned short* __restrict__ Bt,
                                                 const float* __restrict__ bias,
                                                 float* __restrict__ out) {
    __shared__ __align__(16) unsigned short As[8192];
    __shared__ __align__(16) unsigned short Bs[4096];
    const int tid = threadIdx.x;
    const int w = tid >> 6, lane = tid & 63, quad = lane >> 4, l15 = lane & 15;
    const int m0 = blockIdx.y * 128, n0 = blockIdx.x * 64;
    const int wm = (w & 1) * 64, wn = (w >> 1) * 32;
    const int sw = (l15 & 7) << 3;
    f32x4 acc[4][2] = {};
    for (int k0 = 0; k0 < 1024; k0 += 64) {
        __syncthreads();
#pragma unroll
        for (int t = 0; t < 4; ++t) {
            int c = t * 256 + tid;
            int row = c >> 3, jg = ((c & 7) ^ (row & 7)) * 8;
            gl2lds16(&A[(m0 + row) * 1024 + k0 + jg], &As[c * 8]);
            if (t < 2) gl2lds16(&Bt[(n0 + row) * 1024 + k0 + jg], &Bs[c * 8]);
        }
        __syncthreads();
#pragma unroll
        for (int kk = 0; kk < 2; ++kk) {
            bf16x8 af[4], bfr[2];
#pragma unroll
            for (int i = 0; i < 4; ++i)
                af[i] = *reinterpret_cast<const bf16x8*>(
                    &As[(wm + i * 16 + l15) * 64 + ((((kk * 4 + quad) << 3) ^ sw))]);
#pragma unroll
            for (int j = 0; j < 2; ++j)
                bfr[j] = *reinterpret_cast<const bf16x8*>(
                    &Bs[(wn + j * 16 + l15) * 64 + ((((kk * 4 + quad) << 3) ^ sw))]);
#pragma unroll
            for (int i = 0; i < 4; ++i)
#pragma unroll
                for (int j = 0; j < 2; ++j)
                    acc[i][j] = __builtin_amdgcn_mfma_f32_16x16x32_bf16(af[i], bfr[j], acc[i][j], 0, 0, 0);
        }
    }
#pragma unroll
    for (int j = 0; j < 2; ++j) {
        int n = n0 + wn + j * 16 + l15;
        float bv = bias[n];
#pragma unroll
        for (int i = 0; i < 4; ++i)
#pragma unroll
            for (int r = 0; r < 4; ++r) {
                int m = m0 + wm + i * 16 + quad * 4 + r;
                out[m * 1024 + n] = acc[i][j][r] + bv;
            }
    }
}

extern "C" void kernel_launch(void* const* d_in, const int* in_sizes, int n_in,
                              void* d_out, int out_size, void* d_ws, size_t ws_size,
                              hipStream_t stream) {
    const float* x      = (const float*)d_in[0];
    const float* f      = (const float*)d_in[1];
    const float* W_qkv  = (const float*)d_in[2];
    const float* W_proj = (const float*)d_in[3];
    const float* b_proj = (const float*)d_in[4];
    float* out   = (float*)d_out;
    float* attn2 = out + OUT1_OFF;

    char* ws = (char*)d_ws;
    unsigned short* xb     = (unsigned short*)(ws);                 //  8 MiB
    unsigned short* wqkvT  = (unsigned short*)(ws + 8388608);       //  6 MiB (3072,1024)
    unsigned short* wprojT = (unsigned short*)(ws + 14680064);      //  2 MiB (1024,1024)
    unsigned short* qb     = (unsigned short*)(ws + 16777216);      //  8 MiB (B,H,N,D)
    unsigned short* kb     = (unsigned short*)(ws + 25165824);      //  8 MiB (B,H,N,D)
    unsigned short* vtb    = (unsigned short*)(ws + 33554432);      //  8 MiB (B,H,kblk,D,k%64)
    unsigned short* fusedb = (unsigned short*)(ws + 41943040);      //  8 MiB (B*N,C)

    cvt_bf16<<<4096, 256, 0, stream>>>(x, xb, 1048576);
    cvt_t<<<dim3(48, 16), 256, 0, stream>>>(W_qkv, wqkvT, 1024, 3072);
    cvt_t<<<dim3(16, 16), 256, 0, stream>>>(W_proj, wprojT, 1024, 1024);
    gemm_qkv<<<dim3(24, 32), 256, 0, stream>>>(xb, wqkvT, qb, kb, vtb);
    attn_kernel<<<1024, 256, 0, stream>>>(qb, kb, vtb, f, attn2, fusedb);
    gemm_proj<<<dim3(16, 32), 256, 0, stream>>>(fusedb, wprojT, b_proj, out);
}

// Round 6
// 207.690 us; speedup vs baseline: 1.0915x; 1.0915x over previous
//
#include <hip/hip_runtime.h>
#include <hip/hip_bf16.h>

// B=2, N=2048, C=1024, H=16, D=64, SCALE=0.125
// out0 = (attn(x)+f) @ W_proj + b_proj ; out1 = attn2gcn
#define OUT1_OFF 4194304
#define QSCALE 0.1803368801111204f   // 0.125 * log2(e)

typedef __attribute__((ext_vector_type(8))) short bf16x8;
typedef __attribute__((ext_vector_type(4))) float f32x4;

__device__ __forceinline__ unsigned short f2bf(float x) {
    unsigned u = __float_as_uint(x);
    u += 0x7FFFu + ((u >> 16) & 1u);
    return (unsigned short)(u >> 16);
}

// async global->LDS, 16B per lane. dst must be base + lane*16 (contiguous).
__device__ __forceinline__ void gl2lds16(const unsigned short* g, unsigned short* l) {
    __builtin_amdgcn_global_load_lds(
        (const __attribute__((address_space(1))) unsigned int*)g,
        (__attribute__((address_space(3))) unsigned int*)l, 16, 0, 0);
}

__global__ __launch_bounds__(256) void cvt_bf16(const float* __restrict__ s,
                                                unsigned short* __restrict__ d, int n4) {
    int i = blockIdx.x * 256 + threadIdx.x;
    if (i >= n4) return;
    float4 v = reinterpret_cast<const float4*>(s)[i];
    ushort4 o = make_ushort4(f2bf(v.x), f2bf(v.y), f2bf(v.z), f2bf(v.w));
    reinterpret_cast<ushort4*>(d)[i] = o;
}

// Transpose+convert: in (Kd,Nd) f32 -> out (Nd,Kd) bf16.
__global__ __launch_bounds__(256) void cvt_t(const float* __restrict__ in,
                                             unsigned short* __restrict__ out,
                                             int Kd, int Nd) {
    __shared__ float T[64][65];
    const int tid = threadIdx.x;
    const int r0 = blockIdx.y * 64, c0 = blockIdx.x * 64;
    const int tr = tid >> 3, tc = (tid & 7) * 8;
#pragma unroll
    for (int rr = 0; rr < 64; rr += 32) {
        const float4* p = reinterpret_cast<const float4*>(&in[(r0 + tr + rr) * Nd + c0 + tc]);
        float4 v0 = p[0], v1 = p[1];
        T[tr + rr][tc + 0] = v0.x; T[tr + rr][tc + 1] = v0.y;
        T[tr + rr][tc + 2] = v0.z; T[tr + rr][tc + 3] = v0.w;
        T[tr + rr][tc + 4] = v1.x; T[tr + rr][tc + 5] = v1.y;
        T[tr + rr][tc + 6] = v1.z; T[tr + rr][tc + 7] = v1.w;
    }
    __syncthreads();
#pragma unroll
    for (int rr = 0; rr < 64; rr += 32) {
        int orow = tr + rr;
        ushort4 o0 = make_ushort4(f2bf(T[tc + 0][orow]), f2bf(T[tc + 1][orow]),
                                  f2bf(T[tc + 2][orow]), f2bf(T[tc + 3][orow]));
        ushort4 o1 = make_ushort4(f2bf(T[tc + 4][orow]), f2bf(T[tc + 5][orow]),
                                  f2bf(T[tc + 6][orow]), f2bf(T[tc + 7][orow]));
        unsigned short* dst = &out[(c0 + orow) * Kd + r0 + tc];
        *reinterpret_cast<ushort4*>(dst) = o0;
        *reinterpret_cast<ushort4*>(dst + 4) = o1;
    }
}

// ---------------------------------------------------------------------------
// GEMM1 (m97-style): x(4096,1024) @ WqkvT(3072,1024)^T. 128x128 tile, BK=64,
// 4 waves 2x2 (wave 64x64). Epilogue: q(*QSCALE)/k scatter; V goes through an
// LDS transpose (reusing staging LDS) into contiguous 8KB tiles
// (b,h,kblk, d, slot) with slot = key permutation matching attn's S^T
// register layout: actual key a = s*16+quad*4+r  ->  slot = (s>>1)*32 + quad*8
// + (s&1)*4 + r.
// ---------------------------------------------------------------------------
__global__ __launch_bounds__(256) void gemm_qkv(const unsigned short* __restrict__ A,
                                                const unsigned short* __restrict__ Bt,
                                                unsigned short* __restrict__ qb,
                                                unsigned short* __restrict__ kb,
                                                unsigned short* __restrict__ vtb) {
    __shared__ __align__(16) unsigned short Sh[16384];   // As=Sh[0:8192), Bs=Sh[8192:)
    unsigned short* As = Sh;
    unsigned short* Bs = Sh + 8192;
    const int tid = threadIdx.x;
    const int w = tid >> 6, lane = tid & 63, quad = lane >> 4, l15 = lane & 15;
    const int m0 = blockIdx.y * 128, n0 = blockIdx.x * 128;
    const int wm = (w & 1) * 64, wn = (w >> 1) * 64;
    const int sw = (l15 & 7) << 3;
    f32x4 acc[4][4] = {};
    for (int k0 = 0; k0 < 1024; k0 += 64) {
        __syncthreads();
#pragma unroll
        for (int t = 0; t < 4; ++t) {
            int c = t * 256 + tid;
            int row = c >> 3, jg = ((c & 7) ^ (row & 7)) * 8;
            gl2lds16(&A[(m0 + row) * 1024 + k0 + jg], &As[c * 8]);
            gl2lds16(&Bt[(n0 + row) * 1024 + k0 + jg], &Bs[c * 8]);
        }
        __syncthreads();
#pragma unroll
        for (int kk = 0; kk < 2; ++kk) {
            bf16x8 af[4], bfr[4];
#pragma unroll
            for (int i = 0; i < 4; ++i)
                af[i] = *reinterpret_cast<const bf16x8*>(
                    &As[(wm + i * 16 + l15) * 64 + ((((kk * 4 + quad) << 3) ^ sw))]);
#pragma unroll
            for (int j = 0; j < 4; ++j)
                bfr[j] = *reinterpret_cast<const bf16x8*>(
                    &Bs[(wn + j * 16 + l15) * 64 + ((((kk * 4 + quad) << 3) ^ sw))]);
#pragma unroll
            for (int i = 0; i < 4; ++i)
#pragma unroll
                for (int j = 0; j < 4; ++j)
                    acc[i][j] = __builtin_amdgcn_mfma_f32_16x16x32_bf16(af[i], bfr[j], acc[i][j], 0, 0, 0);
        }
    }
    const int nbase = n0 + wn;          // wave's 64-col group (uniform)
    const int t = nbase >> 10;          // 0=q 1=k 2=v
    __syncthreads();                    // all MFMA LDS reads done; Sh reusable
    if (t < 2) {
#pragma unroll
        for (int j = 0; j < 4; ++j) {
            int n = nbase + j * 16 + l15;
            int h = (n & 1023) >> 6, dd = n & 63;
#pragma unroll
            for (int i = 0; i < 4; ++i)
#pragma unroll
                for (int r = 0; r < 4; ++r) {
                    int m = m0 + wm + i * 16 + quad * 4 + r;
                    int b = m >> 11, tok = m & 2047;
                    float v = acc[i][j][r];
                    if (t == 0) qb[(((b * 16 + h) * 2048) + tok) * 64 + dd] = f2bf(v * QSCALE);
                    else        kb[(((b * 16 + h) * 2048) + tok) * 64 + dd] = f2bf(v);
                }
        }
    } else {
        // V: transpose 64 toks x 64 d in LDS -> coalesced tile store.
        unsigned short* scr = Sh + w * 4096;   // 8KB per wave
        const int mb = m0 + wm;                // 64-aligned
        const int b = mb >> 11, kblk = (mb & 2047) >> 6;
        const int h = (nbase & 1023) >> 6;
#pragma unroll
        for (int i = 0; i < 4; ++i) {
            int slot0 = ((i & 2) << 4) | (quad << 3) | ((i & 1) << 2);
#pragma unroll
            for (int j = 0; j < 4; ++j) {
                unsigned short h0 = f2bf(acc[i][j][0]), h1 = f2bf(acc[i][j][1]);
                unsigned short h2 = f2bf(acc[i][j][2]), h3 = f2bf(acc[i][j][3]);
                uint2 pk = make_uint2((unsigned)h0 | ((unsigned)h1 << 16),
                                      (unsigned)h2 | ((unsigned)h3 << 16));
                *reinterpret_cast<uint2*>(&scr[(j * 16 + l15) * 64 + slot0]) = pk;
            }
        }
        asm volatile("s_waitcnt lgkmcnt(0)" ::: "memory");
        unsigned short* vtile = vtb + (((b * 16 + h) * 32) + kblk) * 4096;
#pragma unroll
        for (int p = 0; p < 8; ++p) {
            int idx = (p * 64 + lane) * 8;
            *reinterpret_cast<uint4*>(&vtile[idx]) = *reinterpret_cast<const uint4*>(&scr[idx]);
        }
    }
}

// ---------------------------------------------------------------------------
// Attention v3: grid 512 (16 qtiles x 32 bh XCD-swizzled), 4 waves x 32 q rows.
// S^T = K·Q^T (operand swap): P lands in registers already in A-operand layout
// (q=l15, key=s*16+quad*4+r -> slot=h*32+quad*8+(s&1)*4+r; V pre-permuted to
// slot order by gemm_qkv). NO P LDS round-trip, no fences. Two q-subtiles per
// wave share all K/V fragments (halves LDS bytes per q-row).
// Fixed-max softmax: p=exp2(S) (Q pre-scaled), per-lane row sums (q=l15).
// LDS: 2x8K K + 2x8K V = 32KB.
// ---------------------------------------------------------------------------
__global__ __launch_bounds__(256) void attn_kernel(const unsigned short* __restrict__ qb,
                                                   const unsigned short* __restrict__ kb,
                                                   const unsigned short* __restrict__ vtb,
                                                   const float* __restrict__ f,
                                                   float* __restrict__ attn2_out,
                                                   unsigned short* __restrict__ fusedb) {
    __shared__ __align__(16) unsigned short Ksw[2][4096];
    __shared__ __align__(16) unsigned short Vsw[2][4096];
    const int tid = threadIdx.x;
    const int w = tid >> 6, lane = tid & 63, quad = lane >> 4, l15 = lane & 15;
    const int bid = blockIdx.x;
    const int qtile = bid >> 5;
    const int bh = (bid & 7) * 4 + ((bid >> 3) & 3);   // same bh -> same XCD
    const int q0 = qtile * 128 + w * 32;
    const unsigned short* qrl = &qb[(bh * 2048 + q0 + l15) * 64 + quad * 8];
    const unsigned short* qrh = &qb[(bh * 2048 + q0 + 16 + l15) * 64 + quad * 8];
    bf16x8 ql0 = *reinterpret_cast<const bf16x8*>(qrl);
    bf16x8 ql1 = *reinterpret_cast<const bf16x8*>(qrl + 32);
    bf16x8 qh0 = *reinterpret_cast<const bf16x8*>(qrh);
    bf16x8 qh1 = *reinterpret_cast<const bf16x8*>(qrh + 32);
    const unsigned short* kt0 = kb + bh * 131072;
    const unsigned short* vt0 = vtb + bh * 131072;
    const int c1 = tid, c2 = tid + 256;
    const int gu1 = (((c1 & ~7) | ((c1 & 7) ^ ((c1 >> 3) & 7))) << 3);
    const int gu2 = (((c2 & ~7) | ((c2 & 7) ^ ((c2 >> 3) & 7))) << 3);
    const int sw = (l15 & 7) << 3;
    f32x4 Olo[4] = {}, Ohi[4] = {};
    float sl = 0.f, sh = 0.f;

    gl2lds16(kt0 + gu1, &Ksw[0][c1 * 8]);
    gl2lds16(kt0 + gu2, &Ksw[0][c2 * 8]);
    gl2lds16(vt0 + gu1, &Vsw[0][c1 * 8]);
    gl2lds16(vt0 + gu2, &Vsw[0][c2 * 8]);

    int buf = 0;
    for (int it = 0; it < 32; ++it, buf ^= 1) {
        __syncthreads();    // drains vmcnt: tile[buf] resident; WAR for buf^1
        if (it < 31) {
            int toff = (it + 1) * 4096;
            gl2lds16(kt0 + toff + gu1, &Ksw[buf ^ 1][c1 * 8]);
            gl2lds16(kt0 + toff + gu2, &Ksw[buf ^ 1][c2 * 8]);
            gl2lds16(vt0 + toff + gu1, &Vsw[buf ^ 1][c1 * 8]);
            gl2lds16(vt0 + toff + gu2, &Vsw[buf ^ 1][c2 * 8]);
        }
        f32x4 Tlo[4], Thi[4];
#pragma unroll
        for (int s = 0; s < 4; ++s) {
            int krow = (s * 16 + l15) * 64;
            bf16x8 k0 = *reinterpret_cast<const bf16x8*>(&Ksw[buf][krow + ((quad << 3) ^ sw)]);
            bf16x8 k1 = *reinterpret_cast<const bf16x8*>(&Ksw[buf][krow + (((quad + 4) << 3) ^ sw)]);
            f32x4 z = {};
            z = __builtin_amdgcn_mfma_f32_16x16x32_bf16(k0, ql0, z, 0, 0, 0);
            z = __builtin_amdgcn_mfma_f32_16x16x32_bf16(k1, ql1, z, 0, 0, 0);
            Tlo[s] = z;
            f32x4 z2 = {};
            z2 = __builtin_amdgcn_mfma_f32_16x16x32_bf16(k0, qh0, z2, 0, 0, 0);
            z2 = __builtin_amdgcn_mfma_f32_16x16x32_bf16(k1, qh1, z2, 0, 0, 0);
            Thi[s] = z2;
        }
        bf16x8 plo0, plo1, phi0, phi1;
        {
            float p[4][4];
#pragma unroll
            for (int s = 0; s < 4; ++s)
#pragma unroll
                for (int r = 0; r < 4; ++r) { p[s][r] = __builtin_amdgcn_exp2f(Tlo[s][r]); sl += p[s][r]; }
            uint4 u0, u1;
            u0.x = __builtin_amdgcn_perm(__float_as_uint(p[0][1]), __float_as_uint(p[0][0]), 0x07060302u);
            u0.y = __builtin_amdgcn_perm(__float_as_uint(p[0][3]), __float_as_uint(p[0][2]), 0x07060302u);
            u0.z = __builtin_amdgcn_perm(__float_as_uint(p[1][1]), __float_as_uint(p[1][0]), 0x07060302u);
            u0.w = __builtin_amdgcn_perm(__float_as_uint(p[1][3]), __float_as_uint(p[1][2]), 0x07060302u);
            u1.x = __builtin_amdgcn_perm(__float_as_uint(p[2][1]), __float_as_uint(p[2][0]), 0x07060302u);
            u1.y = __builtin_amdgcn_perm(__float_as_uint(p[2][3]), __float_as_uint(p[2][2]), 0x07060302u);
            u1.z = __builtin_amdgcn_perm(__float_as_uint(p[3][1]), __float_as_uint(p[3][0]), 0x07060302u);
            u1.w = __builtin_amdgcn_perm(__float_as_uint(p[3][3]), __float_as_uint(p[3][2]), 0x07060302u);
            plo0 = __builtin_bit_cast(bf16x8, u0);
            plo1 = __builtin_bit_cast(bf16x8, u1);
        }
        {
            float p[4][4];
#pragma unroll
            for (int s = 0; s < 4; ++s)
#pragma unroll
                for (int r = 0; r < 4; ++r) { p[s][r] = __builtin_amdgcn_exp2f(Thi[s][r]); sh += p[s][r]; }
            uint4 u0, u1;
            u0.x = __builtin_amdgcn_perm(__float_as_uint(p[0][1]), __float_as_uint(p[0][0]), 0x07060302u);
            u0.y = __builtin_amdgcn_perm(__float_as_uint(p[0][3]), __float_as_uint(p[0][2]), 0x07060302u);
            u0.z = __builtin_amdgcn_perm(__float_as_uint(p[1][1]), __float_as_uint(p[1][0]), 0x07060302u);
            u0.w = __builtin_amdgcn_perm(__float_as_uint(p[1][3]), __float_as_uint(p[1][2]), 0x07060302u);
            u1.x = __builtin_amdgcn_perm(__float_as_uint(p[2][1]), __float_as_uint(p[2][0]), 0x07060302u);
            u1.y = __builtin_amdgcn_perm(__float_as_uint(p[2][3]), __float_as_uint(p[2][2]), 0x07060302u);
            u1.z = __builtin_amdgcn_perm(__float_as_uint(p[3][1]), __float_as_uint(p[3][0]), 0x07060302u);
            u1.w = __builtin_amdgcn_perm(__float_as_uint(p[3][3]), __float_as_uint(p[3][2]), 0x07060302u);
            phi0 = __builtin_bit_cast(bf16x8, u0);
            phi1 = __builtin_bit_cast(bf16x8, u1);
        }
#pragma unroll
        for (int c4 = 0; c4 < 4; ++c4) {
            int vrow = (c4 * 16 + l15) * 64;
            bf16x8 v0 = *reinterpret_cast<const bf16x8*>(&Vsw[buf][vrow + ((quad << 3) ^ sw)]);
            bf16x8 v1 = *reinterpret_cast<const bf16x8*>(&Vsw[buf][vrow + (((quad + 4) << 3) ^ sw)]);
            Olo[c4] = __builtin_amdgcn_mfma_f32_16x16x32_bf16(plo0, v0, Olo[c4], 0, 0, 0);
            Olo[c4] = __builtin_amdgcn_mfma_f32_16x16x32_bf16(plo1, v1, Olo[c4], 0, 0, 0);
            Ohi[c4] = __builtin_amdgcn_mfma_f32_16x16x32_bf16(phi0, v0, Ohi[c4], 0, 0, 0);
            Ohi[c4] = __builtin_amdgcn_mfma_f32_16x16x32_bf16(phi1, v1, Ohi[c4], 0, 0, 0);
        }
    }
    sl += __shfl_xor(sl, 16);
    sl += __shfl_xor(sl, 32);
    sh += __shfl_xor(sh, 16);
    sh += __shfl_xor(sh, 32);
    const int b = bh >> 4, h = bh & 15;
#pragma unroll
    for (int r = 0; r < 4; ++r) {
        float invl = 1.f / __shfl(sl, quad * 4 + r, 16);
        float invh = 1.f / __shfl(sh, quad * 4 + r, 16);
        int tokl = q0 + quad * 4 + r;
        int basel = (b * 2048 + tokl) * 1024 + h * 64;
        int baseh = basel + 16 * 1024;
#pragma unroll
        for (int c4 = 0; c4 < 4; ++c4) {
            int col = c4 * 16 + l15;
            float ol = Olo[c4][r] * invl;
            float oh = Ohi[c4][r] * invh;
            attn2_out[basel + col] = ol;
            attn2_out[baseh + col] = oh;
            fusedb[basel + col] = f2bf(ol + f[basel + col]);
            fusedb[baseh + col] = f2bf(oh + f[baseh + col]);
        }
    }
}

// ---------------------------------------------------------------------------
// GEMM2 (m97-style): fused(4096,1024) @ WprojT(1024,1024)^T + bias -> out f32.
// 128x64 tile (4 waves 2x2, wave 64x32), grid (16,32)=512 -> 2 blocks/CU.
// ---------------------------------------------------------------------------
__global__ __launch_bounds__(256) void gemm_proj(const unsigned short* __restrict__ A,
                                                 const unsigned short* __restrict__ Bt,
                                                 const float* __restrict__ bias,
                                                 float* __restrict__ out) {
    __shared__ __align__(16) unsigned short As[8192];
    __shared__ __align__(16) unsigned short Bs[4096];
    const int tid = threadIdx.x;
    const int w = tid >> 6, lane = tid & 63, quad = lane >> 4, l15 = lane & 15;
    const int m0 = blockIdx.y * 128, n0 = blockIdx.x * 64;
    const int wm = (w & 1) * 64, wn = (w >> 1) * 32;
    const int sw = (l15 & 7) << 3;
    f32x4 acc[4][2] = {};
    for (int k0 = 0; k0 < 1024; k0 += 64) {
        __syncthreads();
#pragma unroll
        for (int t = 0; t < 4; ++t) {
            int c = t * 256 + tid;
            int row = c >> 3, jg = ((c & 7) ^ (row & 7)) * 8;
            gl2lds16(&A[(m0 + row) * 1024 + k0 + jg], &As[c * 8]);
            if (t < 2) gl2lds16(&Bt[(n0 + row) * 1024 + k0 + jg], &Bs[c * 8]);
        }
        __syncthreads();
#pragma unroll
        for (int kk = 0; kk < 2; ++kk) {
            bf16x8 af[4], bfr[2];
#pragma unroll
            for (int i = 0; i < 4; ++i)
                af[i] = *reinterpret_cast<const bf16x8*>(
                    &As[(wm + i * 16 + l15) * 64 + ((((kk * 4 + quad) << 3) ^ sw))]);
#pragma unroll
            for (int j = 0; j < 2; ++j)
                bfr[j] = *reinterpret_cast<const bf16x8*>(
                    &Bs[(wn + j * 16 + l15) * 64 + ((((kk * 4 + quad) << 3) ^ sw))]);
#pragma unroll
            for (int i = 0; i < 4; ++i)
#pragma unroll
                for (int j = 0; j < 2; ++j)
                    acc[i][j] = __builtin_amdgcn_mfma_f32_16x16x32_bf16(af[i], bfr[j], acc[i][j], 0, 0, 0);
        }
    }
#pragma unroll
    for (int j = 0; j < 2; ++j) {
        int n = n0 + wn + j * 16 + l15;
        float bv = bias[n];
#pragma unroll
        for (int i = 0; i < 4; ++i)
#pragma unroll
            for (int r = 0; r < 4; ++r) {
                int m = m0 + wm + i * 16 + quad * 4 + r;
                out[m * 1024 + n] = acc[i][j][r] + bv;
            }
    }
}

extern "C" void kernel_launch(void* const* d_in, const int* in_sizes, int n_in,
                              void* d_out, int out_size, void* d_ws, size_t ws_size,
                              hipStream_t stream) {
    const float* x      = (const float*)d_in[0];
    const float* f      = (const float*)d_in[1];
    const float* W_qkv  = (const float*)d_in[2];
    const float* W_proj = (const float*)d_in[3];
    const float* b_proj = (const float*)d_in[4];
    float* out   = (float*)d_out;
    float* attn2 = out + OUT1_OFF;

    char* ws = (char*)d_ws;
    unsigned short* xb     = (unsigned short*)(ws);                 //  8 MiB
    unsigned short* wqkvT  = (unsigned short*)(ws + 8388608);       //  6 MiB (3072,1024)
    unsigned short* wprojT = (unsigned short*)(ws + 14680064);      //  2 MiB (1024,1024)
    unsigned short* qb     = (unsigned short*)(ws + 16777216);      //  8 MiB (B,H,N,D)
    unsigned short* kb     = (unsigned short*)(ws + 25165824);      //  8 MiB (B,H,N,D)
    unsigned short* vtb    = (unsigned short*)(ws + 33554432);      //  8 MiB (B,H,kblk,D,slot)
    unsigned short* fusedb = (unsigned short*)(ws + 41943040);      //  8 MiB (B*N,C)

    cvt_bf16<<<4096, 256, 0, stream>>>(x, xb, 1048576);
    cvt_t<<<dim3(48, 16), 256, 0, stream>>>(W_qkv, wqkvT, 1024, 3072);
    cvt_t<<<dim3(16, 16), 256, 0, stream>>>(W_proj, wprojT, 1024, 1024);
    gemm_qkv<<<dim3(24, 32), 256, 0, stream>>>(xb, wqkvT, qb, kb, vtb);
    attn_kernel<<<512, 256, 0, stream>>>(qb, kb, vtb, f, attn2, fusedb);
    gemm_proj<<<dim3(16, 32), 256, 0, stream>>>(fusedb, wprojT, b_proj, out);
}

// Round 7
// 199.908 us; speedup vs baseline: 1.1340x; 1.0389x over previous
//
#include <hip/hip_runtime.h>
#include <hip/hip_bf16.h>

// B=2, N=2048, C=1024, H=16, D=64, SCALE=0.125
// out0 = (attn(x)+f) @ W_proj + b_proj ; out1 = attn2gcn
#define OUT1_OFF 4194304
#define QSCALE 0.1803368801111204f   // 0.125 * log2(e)

typedef __attribute__((ext_vector_type(8))) short bf16x8;
typedef __attribute__((ext_vector_type(4))) float f32x4;

__device__ __forceinline__ unsigned short f2bf(float x) {
    unsigned u = __float_as_uint(x);
    u += 0x7FFFu + ((u >> 16) & 1u);
    return (unsigned short)(u >> 16);
}

// async global->LDS, 16B per lane. dst must be base + lane*16 (contiguous).
__device__ __forceinline__ void gl2lds16(const unsigned short* g, unsigned short* l) {
    __builtin_amdgcn_global_load_lds(
        (const __attribute__((address_space(1))) unsigned int*)g,
        (__attribute__((address_space(3))) unsigned int*)l, 16, 0, 0);
}

// ---------------------------------------------------------------------------
// prep: region-branched fused converts.
//  bid <  4096          : x f32 -> xb bf16 (vec4)
//  4096 <= bid < 4864   : W_qkv (1024,3072) -> wqkvT (3072,1024) bf16
//  bid >= 4864          : W_proj (1024,1024) -> wprojT (1024,1024) bf16
// ---------------------------------------------------------------------------
__global__ __launch_bounds__(256) void prep(const float* __restrict__ x,
                                            const float* __restrict__ Wqkv,
                                            const float* __restrict__ Wproj,
                                            unsigned short* __restrict__ xb,
                                            unsigned short* __restrict__ wqkvT,
                                            unsigned short* __restrict__ wprojT) {
    __shared__ float T[64][65];
    const int bid = blockIdx.x, tid = threadIdx.x;
    if (bid < 4096) {
        int i = bid * 256 + tid;
        float4 v = reinterpret_cast<const float4*>(x)[i];
        ushort4 o = make_ushort4(f2bf(v.x), f2bf(v.y), f2bf(v.z), f2bf(v.w));
        reinterpret_cast<ushort4*>(xb)[i] = o;
        return;
    }
    const float* in; unsigned short* out; int Nd, bx, by;
    if (bid < 4864) { int t = bid - 4096; in = Wqkv;  out = wqkvT;  Nd = 3072; bx = t % 48; by = t / 48; }
    else            { int t = bid - 4864; in = Wproj; out = wprojT; Nd = 1024; bx = t % 16; by = t / 16; }
    const int Kd = 1024;
    const int r0 = by * 64, c0 = bx * 64;
    const int tr = tid >> 3, tc = (tid & 7) * 8;
#pragma unroll
    for (int rr = 0; rr < 64; rr += 32) {
        const float4* p = reinterpret_cast<const float4*>(&in[(r0 + tr + rr) * Nd + c0 + tc]);
        float4 v0 = p[0], v1 = p[1];
        T[tr + rr][tc + 0] = v0.x; T[tr + rr][tc + 1] = v0.y;
        T[tr + rr][tc + 2] = v0.z; T[tr + rr][tc + 3] = v0.w;
        T[tr + rr][tc + 4] = v1.x; T[tr + rr][tc + 5] = v1.y;
        T[tr + rr][tc + 6] = v1.z; T[tr + rr][tc + 7] = v1.w;
    }
    __syncthreads();
#pragma unroll
    for (int rr = 0; rr < 64; rr += 32) {
        int orow = tr + rr;
        ushort4 o0 = make_ushort4(f2bf(T[tc + 0][orow]), f2bf(T[tc + 1][orow]),
                                  f2bf(T[tc + 2][orow]), f2bf(T[tc + 3][orow]));
        ushort4 o1 = make_ushort4(f2bf(T[tc + 4][orow]), f2bf(T[tc + 5][orow]),
                                  f2bf(T[tc + 6][orow]), f2bf(T[tc + 7][orow]));
        unsigned short* dst = &out[(c0 + orow) * Kd + r0 + tc];
        *reinterpret_cast<ushort4*>(dst) = o0;
        *reinterpret_cast<ushort4*>(dst + 4) = o1;
    }
}

// ---------------------------------------------------------------------------
// GEMM1 (m97-style): x(4096,1024) @ WqkvT(3072,1024)^T. 128x128 tile, BK=64,
// 4 waves 2x2 (wave 64x64). Epilogue: q(*QSCALE)/k scatter; V via LDS
// transpose into contiguous 8KB tiles (b,h,kblk,d,slot), slot permutation
// matching attn's S^T register layout.
// ---------------------------------------------------------------------------
__global__ __launch_bounds__(256) void gemm_qkv(const unsigned short* __restrict__ A,
                                                const unsigned short* __restrict__ Bt,
                                                unsigned short* __restrict__ qb,
                                                unsigned short* __restrict__ kb,
                                                unsigned short* __restrict__ vtb) {
    __shared__ __align__(16) unsigned short Sh[16384];
    unsigned short* As = Sh;
    unsigned short* Bs = Sh + 8192;
    const int tid = threadIdx.x;
    const int w = tid >> 6, lane = tid & 63, quad = lane >> 4, l15 = lane & 15;
    const int m0 = blockIdx.y * 128, n0 = blockIdx.x * 128;
    const int wm = (w & 1) * 64, wn = (w >> 1) * 64;
    const int sw = (l15 & 7) << 3;
    f32x4 acc[4][4] = {};
    for (int k0 = 0; k0 < 1024; k0 += 64) {
        __syncthreads();
#pragma unroll
        for (int t = 0; t < 4; ++t) {
            int c = t * 256 + tid;
            int row = c >> 3, jg = ((c & 7) ^ (row & 7)) * 8;
            gl2lds16(&A[(m0 + row) * 1024 + k0 + jg], &As[c * 8]);
            gl2lds16(&Bt[(n0 + row) * 1024 + k0 + jg], &Bs[c * 8]);
        }
        __syncthreads();
#pragma unroll
        for (int kk = 0; kk < 2; ++kk) {
            bf16x8 af[4], bfr[4];
#pragma unroll
            for (int i = 0; i < 4; ++i)
                af[i] = *reinterpret_cast<const bf16x8*>(
                    &As[(wm + i * 16 + l15) * 64 + ((((kk * 4 + quad) << 3) ^ sw))]);
#pragma unroll
            for (int j = 0; j < 4; ++j)
                bfr[j] = *reinterpret_cast<const bf16x8*>(
                    &Bs[(wn + j * 16 + l15) * 64 + ((((kk * 4 + quad) << 3) ^ sw))]);
#pragma unroll
            for (int i = 0; i < 4; ++i)
#pragma unroll
                for (int j = 0; j < 4; ++j)
                    acc[i][j] = __builtin_amdgcn_mfma_f32_16x16x32_bf16(af[i], bfr[j], acc[i][j], 0, 0, 0);
        }
    }
    const int nbase = n0 + wn;
    const int t = nbase >> 10;
    __syncthreads();
    if (t < 2) {
#pragma unroll
        for (int j = 0; j < 4; ++j) {
            int n = nbase + j * 16 + l15;
            int h = (n & 1023) >> 6, dd = n & 63;
#pragma unroll
            for (int i = 0; i < 4; ++i)
#pragma unroll
                for (int r = 0; r < 4; ++r) {
                    int m = m0 + wm + i * 16 + quad * 4 + r;
                    int b = m >> 11, tok = m & 2047;
                    float v = acc[i][j][r];
                    if (t == 0) qb[(((b * 16 + h) * 2048) + tok) * 64 + dd] = f2bf(v * QSCALE);
                    else        kb[(((b * 16 + h) * 2048) + tok) * 64 + dd] = f2bf(v);
                }
        }
    } else {
        unsigned short* scr = Sh + w * 4096;
        const int mb = m0 + wm;
        const int b = mb >> 11, kblk = (mb & 2047) >> 6;
        const int h = (nbase & 1023) >> 6;
#pragma unroll
        for (int i = 0; i < 4; ++i) {
            int slot0 = ((i & 2) << 4) | (quad << 3) | ((i & 1) << 2);
#pragma unroll
            for (int j = 0; j < 4; ++j) {
                unsigned short h0 = f2bf(acc[i][j][0]), h1 = f2bf(acc[i][j][1]);
                unsigned short h2 = f2bf(acc[i][j][2]), h3 = f2bf(acc[i][j][3]);
                uint2 pk = make_uint2((unsigned)h0 | ((unsigned)h1 << 16),
                                      (unsigned)h2 | ((unsigned)h3 << 16));
                *reinterpret_cast<uint2*>(&scr[(j * 16 + l15) * 64 + slot0]) = pk;
            }
        }
        asm volatile("s_waitcnt lgkmcnt(0)" ::: "memory");
        unsigned short* vtile = vtb + (((b * 16 + h) * 32) + kblk) * 4096;
#pragma unroll
        for (int p = 0; p < 8; ++p) {
            int idx = (p * 64 + lane) * 8;
            *reinterpret_cast<uint4*>(&vtile[idx]) = *reinterpret_cast<const uint4*>(&scr[idx]);
        }
    }
}

// ---------------------------------------------------------------------------
// Attention v4: grid (32 bh, 32 qtiles) = 1024 blocks, 4 waves x 16 q rows.
// S^T = K·Q^T (P lands in A-operand layout; V pre-permuted to slot order).
// Row sums via MFMA with all-ones B (no v_add chain, no shuffles).
// Double-buffered K/V tiles, unroll-2 with literal buffer indices.
// LDS 32KB -> 4 blocks/CU (4 waves/SIMD).
// ---------------------------------------------------------------------------
__global__ __launch_bounds__(256) void attn_kernel(const unsigned short* __restrict__ qb,
                                                   const unsigned short* __restrict__ kb,
                                                   const unsigned short* __restrict__ vtb,
                                                   const float* __restrict__ f,
                                                   float* __restrict__ attn2_out,
                                                   unsigned short* __restrict__ fusedb) {
    __shared__ __align__(16) unsigned short Ksw[2][4096];
    __shared__ __align__(16) unsigned short Vsw[2][4096];
    const int tid = threadIdx.x;
    const int w = tid >> 6, lane = tid & 63, quad = lane >> 4, l15 = lane & 15;
    const int bh = blockIdx.x;          // consecutive bh -> round-robin XCDs (4 bh/XCD)
    const int q0 = blockIdx.y * 64 + w * 16;
    const unsigned short* qr = &qb[(bh * 2048 + q0 + l15) * 64 + quad * 8];
    bf16x8 ql0 = *reinterpret_cast<const bf16x8*>(qr);
    bf16x8 ql1 = *reinterpret_cast<const bf16x8*>(qr + 32);
    const unsigned short* kt0 = kb + bh * 131072;
    const unsigned short* vt0 = vtb + bh * 131072;
    const int c1 = tid, c2 = tid + 256;
    const int gu1 = (((c1 & ~7) | ((c1 & 7) ^ ((c1 >> 3) & 7))) << 3);
    const int gu2 = (((c2 & ~7) | ((c2 & 7) ^ ((c2 >> 3) & 7))) << 3);
    const int sw = (l15 & 7) << 3;
    f32x4 O[4] = {};
    f32x4 asum = {};
    bf16x8 ones;
#pragma unroll
    for (int j = 0; j < 8; ++j) ones[j] = (short)0x3F80;   // bf16 1.0

#define STAGE(IT, BUF) do { int _toff = (IT) * 4096;                    \
        gl2lds16(kt0 + _toff + gu1, &Ksw[BUF][c1 * 8]);                 \
        gl2lds16(kt0 + _toff + gu2, &Ksw[BUF][c2 * 8]);                 \
        gl2lds16(vt0 + _toff + gu1, &Vsw[BUF][c1 * 8]);                 \
        gl2lds16(vt0 + _toff + gu2, &Vsw[BUF][c2 * 8]); } while (0)

    auto body = [&](int buf) {
        f32x4 T[4];
#pragma unroll
        for (int s = 0; s < 4; ++s) {
            const unsigned short* kr = &Ksw[buf][(s * 16 + l15) * 64];
            bf16x8 k0 = *reinterpret_cast<const bf16x8*>(&kr[(quad << 3) ^ sw]);
            bf16x8 k1 = *reinterpret_cast<const bf16x8*>(&kr[((quad + 4) << 3) ^ sw]);
            f32x4 z = {};
            z = __builtin_amdgcn_mfma_f32_16x16x32_bf16(k0, ql0, z, 0, 0, 0);
            z = __builtin_amdgcn_mfma_f32_16x16x32_bf16(k1, ql1, z, 0, 0, 0);
            T[s] = z;
        }
        float p[4][4];
#pragma unroll
        for (int s = 0; s < 4; ++s)
#pragma unroll
            for (int r = 0; r < 4; ++r) p[s][r] = __builtin_amdgcn_exp2f(T[s][r]);
        uint4 u0, u1;
        u0.x = __builtin_amdgcn_perm(__float_as_uint(p[0][1]), __float_as_uint(p[0][0]), 0x07060302u);
        u0.y = __builtin_amdgcn_perm(__float_as_uint(p[0][3]), __float_as_uint(p[0][2]), 0x07060302u);
        u0.z = __builtin_amdgcn_perm(__float_as_uint(p[1][1]), __float_as_uint(p[1][0]), 0x07060302u);
        u0.w = __builtin_amdgcn_perm(__float_as_uint(p[1][3]), __float_as_uint(p[1][2]), 0x07060302u);
        u1.x = __builtin_amdgcn_perm(__float_as_uint(p[2][1]), __float_as_uint(p[2][0]), 0x07060302u);
        u1.y = __builtin_amdgcn_perm(__float_as_uint(p[2][3]), __float_as_uint(p[2][2]), 0x07060302u);
        u1.z = __builtin_amdgcn_perm(__float_as_uint(p[3][1]), __float_as_uint(p[3][0]), 0x07060302u);
        u1.w = __builtin_amdgcn_perm(__float_as_uint(p[3][3]), __float_as_uint(p[3][2]), 0x07060302u);
        bf16x8 pa0 = __builtin_bit_cast(bf16x8, u0);
        bf16x8 pa1 = __builtin_bit_cast(bf16x8, u1);
        asum = __builtin_amdgcn_mfma_f32_16x16x32_bf16(pa0, ones, asum, 0, 0, 0);
        asum = __builtin_amdgcn_mfma_f32_16x16x32_bf16(pa1, ones, asum, 0, 0, 0);
#pragma unroll
        for (int c4 = 0; c4 < 4; ++c4) {
            const unsigned short* vr = &Vsw[buf][(c4 * 16 + l15) * 64];
            bf16x8 v0 = *reinterpret_cast<const bf16x8*>(&vr[(quad << 3) ^ sw]);
            bf16x8 v1 = *reinterpret_cast<const bf16x8*>(&vr[((quad + 4) << 3) ^ sw]);
            O[c4] = __builtin_amdgcn_mfma_f32_16x16x32_bf16(pa0, v0, O[c4], 0, 0, 0);
            O[c4] = __builtin_amdgcn_mfma_f32_16x16x32_bf16(pa1, v1, O[c4], 0, 0, 0);
        }
    };

    STAGE(0, 0);
    for (int it = 0; it < 32; it += 2) {
        __syncthreads();                 // buf0 staged; prior buf1 reads done
        STAGE(it + 1, 1);
        body(0);
        __syncthreads();                 // buf1 staged; buf0 reads done
        if (it + 2 < 32) STAGE(it + 2, 0);
        body(1);
    }
#undef STAGE

    const int b = bh >> 4, h = bh & 15;
#pragma unroll
    for (int r = 0; r < 4; ++r) {
        float inv = 1.f / asum[r];
        int tok = q0 + quad * 4 + r;
        int base = (b * 2048 + tok) * 1024 + h * 64;
#pragma unroll
        for (int c4 = 0; c4 < 4; ++c4) {
            int col = c4 * 16 + l15;
            float o = O[c4][r] * inv;
            attn2_out[base + col] = o;
            fusedb[base + col] = f2bf(o + f[base + col]);
        }
    }
}

// ---------------------------------------------------------------------------
// GEMM2 (m97-style): fused(4096,1024) @ WprojT(1024,1024)^T + bias -> out f32.
// 64x64 tile (4 waves 2x2, wave 32x32), grid (16,64)=1024 -> 4 blocks/CU.
// ---------------------------------------------------------------------------
__global__ __launch_bounds__(256) void gemm_proj(const unsigned short* __restrict__ A,
                                                 const unsigned short* __restrict__ Bt,
                                                 const float* __restrict__ bias,
                                                 float* __restrict__ out) {
    __shared__ __align__(16) unsigned short As[4096];
    __shared__ __align__(16) unsigned short Bs[4096];
    const int tid = threadIdx.x;
    const int w = tid >> 6, lane = tid & 63, quad = lane >> 4, l15 = lane & 15;
    const int m0 = blockIdx.y * 64, n0 = blockIdx.x * 64;
    const int wm = (w & 1) * 32, wn = (w >> 1) * 32;
    const int sw = (l15 & 7) << 3;
    f32x4 acc[2][2] = {};
    for (int k0 = 0; k0 < 1024; k0 += 64) {
        __syncthreads();
#pragma unroll
        for (int t = 0; t < 2; ++t) {
            int c = t * 256 + tid;
            int row = c >> 3, jg = ((c & 7) ^ (row & 7)) * 8;
            gl2lds16(&A[(m0 + row) * 1024 + k0 + jg], &As[c * 8]);
            gl2lds16(&Bt[(n0 + row) * 1024 + k0 + jg], &Bs[c * 8]);
        }
        __syncthreads();
#pragma unroll
        for (int kk = 0; kk < 2; ++kk) {
            bf16x8 af[2], bfr[2];
#pragma unroll
            for (int i = 0; i < 2; ++i)
                af[i] = *reinterpret_cast<const bf16x8*>(
                    &As[(wm + i * 16 + l15) * 64 + ((((kk * 4 + quad) << 3) ^ sw))]);
#pragma unroll
            for (int j = 0; j < 2; ++j)
                bfr[j] = *reinterpret_cast<const bf16x8*>(
                    &Bs[(wn + j * 16 + l15) * 64 + ((((kk * 4 + quad) << 3) ^ sw))]);
#pragma unroll
            for (int i = 0; i < 2; ++i)
#pragma unroll
                for (int j = 0; j < 2; ++j)
                    acc[i][j] = __builtin_amdgcn_mfma_f32_16x16x32_bf16(af[i], bfr[j], acc[i][j], 0, 0, 0);
        }
    }
#pragma unroll
    for (int j = 0; j < 2; ++j) {
        int n = n0 + wn + j * 16 + l15;
        float bv = bias[n];
#pragma unroll
        for (int i = 0; i < 2; ++i)
#pragma unroll
            for (int r = 0; r < 4; ++r) {
                int m = m0 + wm + i * 16 + quad * 4 + r;
                out[m * 1024 + n] = acc[i][j][r] + bv;
            }
    }
}

extern "C" void kernel_launch(void* const* d_in, const int* in_sizes, int n_in,
                              void* d_out, int out_size, void* d_ws, size_t ws_size,
                              hipStream_t stream) {
    const float* x      = (const float*)d_in[0];
    const float* f      = (const float*)d_in[1];
    const float* W_qkv  = (const float*)d_in[2];
    const float* W_proj = (const float*)d_in[3];
    const float* b_proj = (const float*)d_in[4];
    float* out   = (float*)d_out;
    float* attn2 = out + OUT1_OFF;

    char* ws = (char*)d_ws;
    unsigned short* xb     = (unsigned short*)(ws);                 //  8 MiB
    unsigned short* wqkvT  = (unsigned short*)(ws + 8388608);       //  6 MiB (3072,1024)
    unsigned short* wprojT = (unsigned short*)(ws + 14680064);      //  2 MiB (1024,1024)
    unsigned short* qb     = (unsigned short*)(ws + 16777216);      //  8 MiB (B,H,N,D)
    unsigned short* kb     = (unsigned short*)(ws + 25165824);      //  8 MiB (B,H,N,D)
    unsigned short* vtb    = (unsigned short*)(ws + 33554432);      //  8 MiB (B,H,kblk,D,slot)
    unsigned short* fusedb = (unsigned short*)(ws + 41943040);      //  8 MiB (B*N,C)

    prep<<<5120, 256, 0, stream>>>(x, W_qkv, W_proj, xb, wqkvT, wprojT);
    gemm_qkv<<<dim3(24, 32), 256, 0, stream>>>(xb, wqkvT, qb, kb, vtb);
    attn_kernel<<<dim3(32, 32), 256, 0, stream>>>(qb, kb, vtb, f, attn2, fusedb);
    gemm_proj<<<dim3(16, 64), 256, 0, stream>>>(fusedb, wprojT, b_proj, out);
}

// Round 8
// 189.075 us; speedup vs baseline: 1.1990x; 1.0573x over previous
//
#include <hip/hip_runtime.h>
#include <hip/hip_bf16.h>

// B=2, N=2048, C=1024, H=16, D=64, SCALE=0.125
// out0 = (attn(x)+f) @ W_proj + b_proj ; out1 = attn2gcn
#define OUT1_OFF 4194304
#define QSCALE 0.1803368801111204f   // 0.125 * log2(e)

typedef __attribute__((ext_vector_type(8))) short bf16x8;
typedef __attribute__((ext_vector_type(4))) float f32x4;

__device__ __forceinline__ unsigned short f2bf(float x) {
    unsigned u = __float_as_uint(x);
    u += 0x7FFFu + ((u >> 16) & 1u);
    return (unsigned short)(u >> 16);
}

// async global->LDS, 16B per lane. dst must be base + lane*16 (contiguous).
__device__ __forceinline__ void gl2lds16(const unsigned short* g, unsigned short* l) {
    __builtin_amdgcn_global_load_lds(
        (const __attribute__((address_space(1))) unsigned int*)g,
        (__attribute__((address_space(3))) unsigned int*)l, 16, 0, 0);
}

// ---------------------------------------------------------------------------
// prep: region-branched fused converts (x -> bf16; W_qkv, W_proj -> transposed bf16)
// ---------------------------------------------------------------------------
__global__ __launch_bounds__(256) void prep(const float* __restrict__ x,
                                            const float* __restrict__ Wqkv,
                                            const float* __restrict__ Wproj,
                                            unsigned short* __restrict__ xb,
                                            unsigned short* __restrict__ wqkvT,
                                            unsigned short* __restrict__ wprojT) {
    __shared__ float T[64][65];
    const int bid = blockIdx.x, tid = threadIdx.x;
    if (bid < 4096) {
        int i = bid * 256 + tid;
        float4 v = reinterpret_cast<const float4*>(x)[i];
        ushort4 o = make_ushort4(f2bf(v.x), f2bf(v.y), f2bf(v.z), f2bf(v.w));
        reinterpret_cast<ushort4*>(xb)[i] = o;
        return;
    }
    const float* in; unsigned short* out; int Nd, bx, by;
    if (bid < 4864) { int t = bid - 4096; in = Wqkv;  out = wqkvT;  Nd = 3072; bx = t % 48; by = t / 48; }
    else            { int t = bid - 4864; in = Wproj; out = wprojT; Nd = 1024; bx = t % 16; by = t / 16; }
    const int Kd = 1024;
    const int r0 = by * 64, c0 = bx * 64;
    const int tr = tid >> 3, tc = (tid & 7) * 8;
#pragma unroll
    for (int rr = 0; rr < 64; rr += 32) {
        const float4* p = reinterpret_cast<const float4*>(&in[(r0 + tr + rr) * Nd + c0 + tc]);
        float4 v0 = p[0], v1 = p[1];
        T[tr + rr][tc + 0] = v0.x; T[tr + rr][tc + 1] = v0.y;
        T[tr + rr][tc + 2] = v0.z; T[tr + rr][tc + 3] = v0.w;
        T[tr + rr][tc + 4] = v1.x; T[tr + rr][tc + 5] = v1.y;
        T[tr + rr][tc + 6] = v1.z; T[tr + rr][tc + 7] = v1.w;
    }
    __syncthreads();
#pragma unroll
    for (int rr = 0; rr < 64; rr += 32) {
        int orow = tr + rr;
        ushort4 o0 = make_ushort4(f2bf(T[tc + 0][orow]), f2bf(T[tc + 1][orow]),
                                  f2bf(T[tc + 2][orow]), f2bf(T[tc + 3][orow]));
        ushort4 o1 = make_ushort4(f2bf(T[tc + 4][orow]), f2bf(T[tc + 5][orow]),
                                  f2bf(T[tc + 6][orow]), f2bf(T[tc + 7][orow]));
        unsigned short* dst = &out[(c0 + orow) * Kd + r0 + tc];
        *reinterpret_cast<ushort4*>(dst) = o0;
        *reinterpret_cast<ushort4*>(dst + 4) = o1;
    }
}

// ---------------------------------------------------------------------------
// GEMM1: x(4096,1024) @ WqkvT(3072,1024)^T. 128x128 tile, BK=64, 4 waves 2x2.
// q/k waves swap MFMA operands so the register quad runs along d -> LDS
// transpose (stride-72 scratch, conflict-free) -> fully coalesced uint4 tile
// stores. V same scratch scheme, key-slot permuted to attn's S^T layout.
// ---------------------------------------------------------------------------
__global__ __launch_bounds__(256) void gemm_qkv(const unsigned short* __restrict__ A,
                                                const unsigned short* __restrict__ Bt,
                                                unsigned short* __restrict__ qb,
                                                unsigned short* __restrict__ kb,
                                                unsigned short* __restrict__ vtb) {
    __shared__ __align__(16) unsigned short Sh[18432];   // 36 KB: staging 32K, epi scratch 4x4608
    unsigned short* As = Sh;
    unsigned short* Bs = Sh + 8192;
    const int tid = threadIdx.x;
    const int w = tid >> 6, lane = tid & 63, quad = lane >> 4, l15 = lane & 15;
    const int m0 = blockIdx.y * 128, n0 = blockIdx.x * 128;
    const int wm = (w & 1) * 64, wn = (w >> 1) * 64;
    const int nbase = n0 + wn;
    const int t = nbase >> 10;           // 0=q 1=k 2=v (block-uniform)
    const bool qk = (t < 2);
    const int sw = (l15 & 7) << 3;
    f32x4 acc[4][4] = {};
    for (int k0 = 0; k0 < 1024; k0 += 64) {
        __syncthreads();
#pragma unroll
        for (int tt = 0; tt < 4; ++tt) {
            int c = tt * 256 + tid;
            int row = c >> 3, jg = ((c & 7) ^ (row & 7)) * 8;
            gl2lds16(&A[(m0 + row) * 1024 + k0 + jg], &As[c * 8]);
            gl2lds16(&Bt[(n0 + row) * 1024 + k0 + jg], &Bs[c * 8]);
        }
        __syncthreads();
#pragma unroll
        for (int kk = 0; kk < 2; ++kk) {
            bf16x8 af[4], bfr[4];
#pragma unroll
            for (int i = 0; i < 4; ++i)
                af[i] = *reinterpret_cast<const bf16x8*>(
                    &As[(wm + i * 16 + l15) * 64 + ((((kk * 4 + quad) << 3) ^ sw))]);
#pragma unroll
            for (int j = 0; j < 4; ++j)
                bfr[j] = *reinterpret_cast<const bf16x8*>(
                    &Bs[(wn + j * 16 + l15) * 64 + ((((kk * 4 + quad) << 3) ^ sw))]);
            if (qk) {   // D[row=d, col=tok]
#pragma unroll
                for (int i = 0; i < 4; ++i)
#pragma unroll
                    for (int j = 0; j < 4; ++j)
                        acc[i][j] = __builtin_amdgcn_mfma_f32_16x16x32_bf16(bfr[j], af[i], acc[i][j], 0, 0, 0);
            } else {    // D[row=tok, col=d]
#pragma unroll
                for (int i = 0; i < 4; ++i)
#pragma unroll
                    for (int j = 0; j < 4; ++j)
                        acc[i][j] = __builtin_amdgcn_mfma_f32_16x16x32_bf16(af[i], bfr[j], acc[i][j], 0, 0, 0);
            }
        }
    }
    __syncthreads();                     // staging LDS reusable as scratch
    unsigned short* scr = Sh + w * 4608; // 64 rows x 72 ush (stride 144B, conflict-free)
    const int mb = m0 + wm;
    const int b = mb >> 11;
    const int h = (nbase & 1023) >> 6;
    const float sc = (t == 0) ? QSCALE : 1.f;
    if (qk) {
        // acc[i][j][r]: tok_local = i*16+l15 ; d = j*16+quad*4+r (4 consecutive d)
#pragma unroll
        for (int i = 0; i < 4; ++i) {
            int row = i * 16 + l15;
#pragma unroll
            for (int j = 0; j < 4; ++j) {
                unsigned short h0 = f2bf(acc[i][j][0] * sc), h1 = f2bf(acc[i][j][1] * sc);
                unsigned short h2 = f2bf(acc[i][j][2] * sc), h3 = f2bf(acc[i][j][3] * sc);
                uint2 pk = make_uint2((unsigned)h0 | ((unsigned)h1 << 16),
                                      (unsigned)h2 | ((unsigned)h3 << 16));
                *reinterpret_cast<uint2*>(&scr[row * 72 + j * 16 + quad * 4]) = pk;
            }
        }
        asm volatile("s_waitcnt lgkmcnt(0)" ::: "memory");
        unsigned short* dst = (t == 0 ? qb : kb) + (((b * 16 + h) * 2048) + (mb & 2047)) * 64;
#pragma unroll
        for (int p = 0; p < 8; ++p) {
            int idx = p * 64 + lane;
            *reinterpret_cast<uint4*>(&dst[idx * 8]) =
                *reinterpret_cast<const uint4*>(&scr[(idx >> 3) * 72 + (idx & 7) * 8]);
        }
    } else {
        // V: scratch [d][slot], slot = key permutation matching attn S^T layout
        const int kblk = (mb & 2047) >> 6;
#pragma unroll
        for (int i = 0; i < 4; ++i) {
            int slot0 = ((i & 2) << 4) | (quad << 3) | ((i & 1) << 2);
#pragma unroll
            for (int j = 0; j < 4; ++j) {
                unsigned short h0 = f2bf(acc[i][j][0]), h1 = f2bf(acc[i][j][1]);
                unsigned short h2 = f2bf(acc[i][j][2]), h3 = f2bf(acc[i][j][3]);
                uint2 pk = make_uint2((unsigned)h0 | ((unsigned)h1 << 16),
                                      (unsigned)h2 | ((unsigned)h3 << 16));
                *reinterpret_cast<uint2*>(&scr[(j * 16 + l15) * 72 + slot0]) = pk;
            }
        }
        asm volatile("s_waitcnt lgkmcnt(0)" ::: "memory");
        unsigned short* vtile = vtb + (((b * 16 + h) * 32) + kblk) * 4096;
#pragma unroll
        for (int p = 0; p < 8; ++p) {
            int idx = p * 64 + lane;
            *reinterpret_cast<uint4*>(&vtile[idx * 8]) =
                *reinterpret_cast<const uint4*>(&scr[(idx >> 3) * 72 + (idx & 7) * 8]);
        }
    }
}

// ---------------------------------------------------------------------------
// Attention v5: grid (32 bh, 16 qtiles) = 512 blocks, 8 waves x 16 q = 128 q.
// Halves K/V staging vs R7 (16 qtiles). S^T = K·Q^T; sums via ones-MFMA.
// Double-buffered K/V, 1 global_load_lds per thread per tile. LDS 32 KB.
// ---------------------------------------------------------------------------
__global__ __launch_bounds__(512) void attn_kernel(const unsigned short* __restrict__ qb,
                                                   const unsigned short* __restrict__ kb,
                                                   const unsigned short* __restrict__ vtb,
                                                   const float* __restrict__ f,
                                                   float* __restrict__ attn2_out,
                                                   unsigned short* __restrict__ fusedb) {
    __shared__ __align__(16) unsigned short Ksw[2][4096];
    __shared__ __align__(16) unsigned short Vsw[2][4096];
    const int tid = threadIdx.x;
    const int w = tid >> 6, lane = tid & 63, quad = lane >> 4, l15 = lane & 15;
    const int bh = blockIdx.x;          // bh mod 8 = XCD -> K/V L2-resident per XCD
    const int q0 = blockIdx.y * 128 + w * 16;
    const unsigned short* qr = &qb[(bh * 2048 + q0 + l15) * 64 + quad * 8];
    bf16x8 ql0 = *reinterpret_cast<const bf16x8*>(qr);
    bf16x8 ql1 = *reinterpret_cast<const bf16x8*>(qr + 32);
    const unsigned short* kt0 = kb + bh * 131072;
    const unsigned short* vt0 = vtb + bh * 131072;
    const int c = tid;
    const int gu = (((c & ~7) | ((c & 7) ^ ((c >> 3) & 7))) << 3);
    const int sw = (l15 & 7) << 3;
    f32x4 O[4] = {};
    f32x4 asum = {};
    bf16x8 ones;
#pragma unroll
    for (int j = 0; j < 8; ++j) ones[j] = (short)0x3F80;   // bf16 1.0

#define STAGE(IT, BUF) do { int _toff = (IT) * 4096;                    \
        gl2lds16(kt0 + _toff + gu, &Ksw[BUF][c * 8]);                   \
        gl2lds16(vt0 + _toff + gu, &Vsw[BUF][c * 8]); } while (0)

    auto body = [&](int buf) {
        f32x4 T[4];
#pragma unroll
        for (int s = 0; s < 4; ++s) {
            const unsigned short* kr = &Ksw[buf][(s * 16 + l15) * 64];
            bf16x8 k0 = *reinterpret_cast<const bf16x8*>(&kr[(quad << 3) ^ sw]);
            bf16x8 k1 = *reinterpret_cast<const bf16x8*>(&kr[((quad + 4) << 3) ^ sw]);
            f32x4 z = {};
            z = __builtin_amdgcn_mfma_f32_16x16x32_bf16(k0, ql0, z, 0, 0, 0);
            z = __builtin_amdgcn_mfma_f32_16x16x32_bf16(k1, ql1, z, 0, 0, 0);
            T[s] = z;
        }
        float p[4][4];
#pragma unroll
        for (int s = 0; s < 4; ++s)
#pragma unroll
            for (int r = 0; r < 4; ++r) p[s][r] = __builtin_amdgcn_exp2f(T[s][r]);
        uint4 u0, u1;
        u0.x = __builtin_amdgcn_perm(__float_as_uint(p[0][1]), __float_as_uint(p[0][0]), 0x07060302u);
        u0.y = __builtin_amdgcn_perm(__float_as_uint(p[0][3]), __float_as_uint(p[0][2]), 0x07060302u);
        u0.z = __builtin_amdgcn_perm(__float_as_uint(p[1][1]), __float_as_uint(p[1][0]), 0x07060302u);
        u0.w = __builtin_amdgcn_perm(__float_as_uint(p[1][3]), __float_as_uint(p[1][2]), 0x07060302u);
        u1.x = __builtin_amdgcn_perm(__float_as_uint(p[2][1]), __float_as_uint(p[2][0]), 0x07060302u);
        u1.y = __builtin_amdgcn_perm(__float_as_uint(p[2][3]), __float_as_uint(p[2][2]), 0x07060302u);
        u1.z = __builtin_amdgcn_perm(__float_as_uint(p[3][1]), __float_as_uint(p[3][0]), 0x07060302u);
        u1.w = __builtin_amdgcn_perm(__float_as_uint(p[3][3]), __float_as_uint(p[3][2]), 0x07060302u);
        bf16x8 pa0 = __builtin_bit_cast(bf16x8, u0);
        bf16x8 pa1 = __builtin_bit_cast(bf16x8, u1);
        asum = __builtin_amdgcn_mfma_f32_16x16x32_bf16(pa0, ones, asum, 0, 0, 0);
        asum = __builtin_amdgcn_mfma_f32_16x16x32_bf16(pa1, ones, asum, 0, 0, 0);
#pragma unroll
        for (int c4 = 0; c4 < 4; ++c4) {
            const unsigned short* vr = &Vsw[buf][(c4 * 16 + l15) * 64];
            bf16x8 v0 = *reinterpret_cast<const bf16x8*>(&vr[(quad << 3) ^ sw]);
            bf16x8 v1 = *reinterpret_cast<const bf16x8*>(&vr[((quad + 4) << 3) ^ sw]);
            O[c4] = __builtin_amdgcn_mfma_f32_16x16x32_bf16(pa0, v0, O[c4], 0, 0, 0);
            O[c4] = __builtin_amdgcn_mfma_f32_16x16x32_bf16(pa1, v1, O[c4], 0, 0, 0);
        }
    };

    STAGE(0, 0);
    for (int it = 0; it < 32; it += 2) {
        __syncthreads();                 // buf0 staged; prior buf1 reads done
        STAGE(it + 1, 1);
        body(0);
        __syncthreads();                 // buf1 staged; buf0 reads done
        if (it + 2 < 32) STAGE(it + 2, 0);
        body(1);
    }
#undef STAGE

    const int b = bh >> 4, h = bh & 15;
#pragma unroll
    for (int r = 0; r < 4; ++r) {
        float inv = 1.f / asum[r];
        int tok = q0 + quad * 4 + r;
        int base = (b * 2048 + tok) * 1024 + h * 64;
#pragma unroll
        for (int c4 = 0; c4 < 4; ++c4) {
            int col = c4 * 16 + l15;
            float o = O[c4][r] * inv;
            attn2_out[base + col] = o;
            fusedb[base + col] = f2bf(o + f[base + col]);
        }
    }
}

// ---------------------------------------------------------------------------
// GEMM2: fused(4096,1024) @ WprojT(1024,1024)^T + bias. 128x64 tile,
// grid (16,32)=512 -> 2 blocks/CU, wave 64x32.
// ---------------------------------------------------------------------------
__global__ __launch_bounds__(256) void gemm_proj(const unsigned short* __restrict__ A,
                                                 const unsigned short* __restrict__ Bt,
                                                 const float* __restrict__ bias,
                                                 float* __restrict__ out) {
    __shared__ __align__(16) unsigned short As[8192];
    __shared__ __align__(16) unsigned short Bs[4096];
    const int tid = threadIdx.x;
    const int w = tid >> 6, lane = tid & 63, quad = lane >> 4, l15 = lane & 15;
    const int m0 = blockIdx.y * 128, n0 = blockIdx.x * 64;
    const int wm = (w & 1) * 64, wn = (w >> 1) * 32;
    const int sw = (l15 & 7) << 3;
    f32x4 acc[4][2] = {};
    for (int k0 = 0; k0 < 1024; k0 += 64) {
        __syncthreads();
#pragma unroll
        for (int t = 0; t < 4; ++t) {
            int c = t * 256 + tid;
            int row = c >> 3, jg = ((c & 7) ^ (row & 7)) * 8;
            gl2lds16(&A[(m0 + row) * 1024 + k0 + jg], &As[c * 8]);
            if (t < 2) gl2lds16(&Bt[(n0 + row) * 1024 + k0 + jg], &Bs[c * 8]);
        }
        __syncthreads();
#pragma unroll
        for (int kk = 0; kk < 2; ++kk) {
            bf16x8 af[4], bfr[2];
#pragma unroll
            for (int i = 0; i < 4; ++i)
                af[i] = *reinterpret_cast<const bf16x8*>(
                    &As[(wm + i * 16 + l15) * 64 + ((((kk * 4 + quad) << 3) ^ sw))]);
#pragma unroll
            for (int j = 0; j < 2; ++j)
                bfr[j] = *reinterpret_cast<const bf16x8*>(
                    &Bs[(wn + j * 16 + l15) * 64 + ((((kk * 4 + quad) << 3) ^ sw))]);
#pragma unroll
            for (int i = 0; i < 4; ++i)
#pragma unroll
                for (int j = 0; j < 2; ++j)
                    acc[i][j] = __builtin_amdgcn_mfma_f32_16x16x32_bf16(af[i], bfr[j], acc[i][j], 0, 0, 0);
        }
    }
#pragma unroll
    for (int j = 0; j < 2; ++j) {
        int n = n0 + wn + j * 16 + l15;
        float bv = bias[n];
#pragma unroll
        for (int i = 0; i < 4; ++i)
#pragma unroll
            for (int r = 0; r < 4; ++r) {
                int m = m0 + wm + i * 16 + quad * 4 + r;
                out[m * 1024 + n] = acc[i][j][r] + bv;
            }
    }
}

extern "C" void kernel_launch(void* const* d_in, const int* in_sizes, int n_in,
                              void* d_out, int out_size, void* d_ws, size_t ws_size,
                              hipStream_t stream) {
    const float* x      = (const float*)d_in[0];
    const float* f      = (const float*)d_in[1];
    const float* W_qkv  = (const float*)d_in[2];
    const float* W_proj = (const float*)d_in[3];
    const float* b_proj = (const float*)d_in[4];
    float* out   = (float*)d_out;
    float* attn2 = out + OUT1_OFF;

    char* ws = (char*)d_ws;
    unsigned short* xb     = (unsigned short*)(ws);                 //  8 MiB
    unsigned short* wqkvT  = (unsigned short*)(ws + 8388608);       //  6 MiB (3072,1024)
    unsigned short* wprojT = (unsigned short*)(ws + 14680064);      //  2 MiB (1024,1024)
    unsigned short* qb     = (unsigned short*)(ws + 16777216);      //  8 MiB (B,H,N,D)
    unsigned short* kb     = (unsigned short*)(ws + 25165824);      //  8 MiB (B,H,N,D)
    unsigned short* vtb    = (unsigned short*)(ws + 33554432);      //  8 MiB (B,H,kblk,D,slot)
    unsigned short* fusedb = (unsigned short*)(ws + 41943040);      //  8 MiB (B*N,C)

    prep<<<5120, 256, 0, stream>>>(x, W_qkv, W_proj, xb, wqkvT, wprojT);
    gemm_qkv<<<dim3(24, 32), 256, 0, stream>>>(xb, wqkvT, qb, kb, vtb);
    attn_kernel<<<dim3(32, 16), 512, 0, stream>>>(qb, kb, vtb, f, attn2, fusedb);
    gemm_proj<<<dim3(16, 32), 256, 0, stream>>>(fusedb, wprojT, b_proj, out);
}